// Round 1
// baseline (1056.773 us; speedup 1.0000x reference)
//
#include <hip/hip_runtime.h>
#include <math.h>

#define N_NODES 50000
#define N_EDGES 800000
#define ET (N_EDGES + N_NODES)   // 850000 with self loops
#define NF 512
#define HC 64
#define NH 8
#define D1 512                   // NH*HC
#define NC 16
#define NEG_SLOPE 0.2f

// ---------------- GEMM1: h1 = x @ W1  (fp32, 64x64 tile, 4x4/thread) ----------
#define TM 64
#define TN 64
#define TK 16

__global__ __launch_bounds__(256) void k_gemm1(const float* __restrict__ A,
                                               const float* __restrict__ B,
                                               float* __restrict__ C, int M) {
  __shared__ float As[TK][TM + 4];   // stride 68 floats -> 272B, 16B aligned
  __shared__ float Bs[TK][TN];
  const int tid = threadIdx.x;
  const int tx = tid & 15, ty = tid >> 4;
  const int bm = blockIdx.y * TM;
  const int bn = blockIdx.x * TN;
  const int am = tid >> 2;          // 0..63
  const int ak = (tid & 3) * 4;     // 0,4,8,12
  const int br = tid >> 4;          // 0..15
  const int bc = (tid & 15) * 4;    // 0..60
  const int arow = bm + am;
  float acc[4][4] = {};
  for (int k0 = 0; k0 < NF; k0 += TK) {
    float4 av;
    if (arow < M) av = *(const float4*)&A[(size_t)arow * NF + k0 + ak];
    else          av = make_float4(0.f, 0.f, 0.f, 0.f);
    float4 bv = *(const float4*)&B[(size_t)(k0 + br) * D1 + bn + bc];
    As[ak + 0][am] = av.x; As[ak + 1][am] = av.y;
    As[ak + 2][am] = av.z; As[ak + 3][am] = av.w;
    *(float4*)&Bs[br][bc] = bv;
    __syncthreads();
#pragma unroll
    for (int kk = 0; kk < TK; ++kk) {
      float4 a4 = *(const float4*)&As[kk][ty * 4];
      float4 b4 = *(const float4*)&Bs[kk][tx * 4];
      float aa[4] = {a4.x, a4.y, a4.z, a4.w};
      float bb[4] = {b4.x, b4.y, b4.z, b4.w};
#pragma unroll
      for (int i = 0; i < 4; ++i)
#pragma unroll
        for (int j = 0; j < 4; ++j) acc[i][j] += aa[i] * bb[j];
    }
    __syncthreads();
  }
#pragma unroll
  for (int i = 0; i < 4; ++i) {
    int row = bm + ty * 4 + i;
    if (row < M) {
      float4 v = make_float4(acc[i][0], acc[i][1], acc[i][2], acc[i][3]);
      *(float4*)&C[(size_t)row * D1 + bn + tx * 4] = v;
    }
  }
}

// ---------------- per-node attention logits, layer 1 -------------------------
__global__ void k_alphas1(const float* __restrict__ h1,
                          const float* __restrict__ a_src,
                          const float* __restrict__ a_dst,
                          float* __restrict__ as1, float* __restrict__ ad1) {
  int i = blockIdx.x * 256 + threadIdx.x;
  if (i >= N_NODES * NH) return;
  int n = i >> 3, hd = i & 7;
  const float* hp  = h1 + (size_t)n * D1 + hd * HC;
  const float* aw  = a_src + hd * HC;
  const float* dw  = a_dst + hd * HC;
  float s = 0.f, d = 0.f;
#pragma unroll
  for (int c = 0; c < HC; c += 4) {
    float4 v  = *(const float4*)&hp[c];
    float4 a4 = *(const float4*)&aw[c];
    float4 d4 = *(const float4*)&dw[c];
    s += v.x * a4.x + v.y * a4.y + v.z * a4.z + v.w * a4.w;
    d += v.x * d4.x + v.y * d4.y + v.z * d4.z + v.w * d4.w;
  }
  as1[i] = s; ad1[i] = d;
}

// ---------------- CSR construction -------------------------------------------
__global__ void k_degree(const int* __restrict__ ei, int* __restrict__ deg) {
  int i = blockIdx.x * 256 + threadIdx.x;
  if (i >= ET) return;
  int dst = (i < N_EDGES) ? ei[N_EDGES + i] : (i - N_EDGES);
  atomicAdd(&deg[dst], 1);
}

__global__ void k_reduce(const int* __restrict__ deg, int* __restrict__ bsums) {
  __shared__ int s[1024];
  int i = blockIdx.x * 1024 + threadIdx.x;
  s[threadIdx.x] = (i < N_NODES) ? deg[i] : 0;
  __syncthreads();
  for (int off = 512; off > 0; off >>= 1) {
    if (threadIdx.x < off) s[threadIdx.x] += s[threadIdx.x + off];
    __syncthreads();
  }
  if (threadIdx.x == 0) bsums[blockIdx.x] = s[0];
}

__global__ void k_scan_small(int* __restrict__ bsums, int nb) {
  int lane = threadIdx.x;
  int v = (lane < nb) ? bsums[lane] : 0;
  int orig = v;
  for (int off = 1; off < 64; off <<= 1) {
    int u = __shfl_up(v, off);
    if (lane >= off) v += u;
  }
  __syncthreads();
  if (lane < nb) bsums[lane] = v - orig;   // exclusive
}

__global__ void k_scan_final(const int* __restrict__ deg,
                             const int* __restrict__ bsums_ex,
                             int* __restrict__ rowp, int* __restrict__ pos) {
  __shared__ int s[1024];
  int i = blockIdx.x * 1024 + threadIdx.x;
  int v = (i < N_NODES) ? deg[i] : 0;
  s[threadIdx.x] = v;
  __syncthreads();
  for (int off = 1; off < 1024; off <<= 1) {
    int t = (threadIdx.x >= off) ? s[threadIdx.x - off] : 0;
    __syncthreads();
    s[threadIdx.x] += t;
    __syncthreads();
  }
  int inc = s[threadIdx.x];
  int ex  = inc - v + bsums_ex[blockIdx.x];
  if (i < N_NODES) { rowp[i] = ex; pos[i] = ex; }
  if (i == N_NODES - 1) rowp[N_NODES] = ex + v;
}

__global__ void k_scatter(const int* __restrict__ ei, int* __restrict__ pos,
                          int* __restrict__ csr) {
  int i = blockIdx.x * 256 + threadIdx.x;
  if (i >= ET) return;
  int s, d;
  if (i < N_EDGES) { s = ei[i]; d = ei[N_EDGES + i]; }
  else             { s = d = i - N_EDGES; }
  int slot = atomicAdd(&pos[d], 1);
  csr[slot] = s;
}

// ---------------- layer-1 aggregation: one wave per destination node ---------
__global__ __launch_bounds__(256) void k_agg1(const float* __restrict__ h1,
                                              const float* __restrict__ as1,
                                              const float* __restrict__ ad1,
                                              const int* __restrict__ rowp,
                                              const int* __restrict__ csr,
                                              const float* __restrict__ b1,
                                              float* __restrict__ emb) {
  const int wid  = threadIdx.x >> 6;
  const int lane = threadIdx.x & 63;
  const int node = blockIdx.x * 4 + wid;
  if (node >= N_NODES) return;
  const int start = rowp[node], end = rowp[node + 1];

  // pass 1: per-head denominators; lane = (edge_sub, head)
  const int hd8 = lane & 7;
  const float adv = ad1[node * NH + hd8];
  float den = 0.f;
  for (int base = start; base < end; base += 8) {
    int slot = base + (lane >> 3);
    if (slot < end) {
      int src = csr[slot];
      float e = as1[src * NH + hd8] + adv;
      e = (e >= 0.f) ? e : NEG_SLOPE * e;
      den += __expf(e);
    }
  }
  den += __shfl_xor(den, 8);
  den += __shfl_xor(den, 16);
  den += __shfl_xor(den, 32);
  float rd = 1.f / den;                // lane l holds head (l & 7)
  float rden[NH], adu[NH];
#pragma unroll
  for (int hd = 0; hd < NH; ++hd) {
    rden[hd] = __shfl(rd, hd);
    adu[hd]  = __shfl(adv, hd);
  }

  // pass 2: weighted gather-sum; lane owns channel (hd*64+lane)
  float acc[NH] = {};
  for (int j = start; j < end; ++j) {
    int src = csr[j];
    const float* hrow = h1 + (size_t)src * D1;
    const float* arow = as1 + src * NH;
#pragma unroll
    for (int hd = 0; hd < NH; ++hd) {
      float e = arow[hd] + adu[hd];
      e = (e >= 0.f) ? e : NEG_SLOPE * e;
      float w = __expf(e) * rden[hd];
      acc[hd] += w * hrow[hd * HC + lane];
    }
  }
#pragma unroll
  for (int hd = 0; hd < NH; ++hd)
    emb[(size_t)node * D1 + hd * HC + lane] = acc[hd] + b1[hd * HC + lane];
}

// ---------------- layer 2: h2 = elu(emb) @ W2 --------------------------------
__global__ __launch_bounds__(256) void k_gemm2(const float* __restrict__ emb,
                                               const float* __restrict__ W2,
                                               float* __restrict__ h2) {
  __shared__ float sx[D1];
  __shared__ float red[16][17];
  const int node = blockIdx.x;
  const int tid = threadIdx.x;
#pragma unroll
  for (int v = 0; v < 2; ++v) {
    int c = tid + v * 256;
    float x = emb[(size_t)node * D1 + c];
    sx[c] = (x > 0.f) ? x : expm1f(x);
  }
  __syncthreads();
  const int c = tid & 15;   // output channel
  const int g = tid >> 4;   // 0..15 partial group
  float s = 0.f;
  for (int k = g; k < D1; k += 16) s += sx[k] * W2[k * NC + c];
  red[c][g] = s;
  __syncthreads();
  if (tid < 16) {
    float t = 0.f;
#pragma unroll
    for (int g2 = 0; g2 < 16; ++g2) t += red[tid][g2];
    h2[(size_t)node * NC + tid] = t;
  }
}

__global__ void k_alphas2(const float* __restrict__ h2,
                          const float* __restrict__ a_src,
                          const float* __restrict__ a_dst,
                          float* __restrict__ as2, float* __restrict__ ad2) {
  int n = blockIdx.x * 256 + threadIdx.x;
  if (n >= N_NODES) return;
  float s = 0.f, d = 0.f;
#pragma unroll
  for (int c = 0; c < NC; ++c) {
    float v = h2[(size_t)n * NC + c];
    s += v * a_src[c];
    d += v * a_dst[c];
  }
  as2[n] = s; ad2[n] = d;
}

__global__ __launch_bounds__(256) void k_agg2(const float* __restrict__ h2,
                                              const float* __restrict__ as2,
                                              const float* __restrict__ ad2,
                                              const int* __restrict__ rowp,
                                              const int* __restrict__ csr,
                                              const float* __restrict__ b2,
                                              float* __restrict__ logits) {
  const int wid  = threadIdx.x >> 6;
  const int lane = threadIdx.x & 63;
  const int node = blockIdx.x * 4 + wid;
  if (node >= N_NODES) return;
  const int start = rowp[node], end = rowp[node + 1];
  const float adv = ad2[node];

  float den = 0.f;
  for (int j = start + lane; j < end; j += 64) {
    int src = csr[j];
    float e = as2[src] + adv;
    e = (e >= 0.f) ? e : NEG_SLOPE * e;
    den += __expf(e);
  }
  for (int off = 32; off > 0; off >>= 1) den += __shfl_xor(den, off);
  float rd = 1.f / den;

  float acc = 0.f;
  for (int base = start; base < end; base += 4) {
    int j = base + (lane >> 4);
    if (j < end) {
      int src = csr[j];
      float e = as2[src] + adv;
      e = (e >= 0.f) ? e : NEG_SLOPE * e;
      float alpha = __expf(e) * rd;
      acc += alpha * h2[(size_t)src * NC + (lane & 15)];
    }
  }
  acc += __shfl_xor(acc, 16);
  acc += __shfl_xor(acc, 32);
  if (lane < 16) logits[(size_t)node * NC + lane] = acc + b2[lane];
}

// ---------------- launcher ---------------------------------------------------
extern "C" void kernel_launch(void* const* d_in, const int* in_sizes, int n_in,
                              void* d_out, int out_size, void* d_ws, size_t ws_size,
                              hipStream_t stream) {
  const float* x      = (const float*)d_in[0];
  const int*   ei     = (const int*)d_in[1];
  const float* w1     = (const float*)d_in[2];
  const float* a_src1 = (const float*)d_in[3];
  const float* a_dst1 = (const float*)d_in[4];
  const float* b1     = (const float*)d_in[5];
  const float* w2     = (const float*)d_in[6];
  const float* a_src2 = (const float*)d_in[7];
  const float* a_dst2 = (const float*)d_in[8];
  const float* b2     = (const float*)d_in[9];

  char* w = (char*)d_ws;
  float* h1  = (float*)w;  w += (size_t)N_NODES * D1 * 4;     // 102.4 MB
  float* as1 = (float*)w;  w += (size_t)N_NODES * NH * 4;
  float* ad1 = (float*)w;  w += (size_t)N_NODES * NH * 4;
  float* h2  = (float*)w;  w += (size_t)N_NODES * NC * 4;
  float* as2 = (float*)w;  w += (size_t)N_NODES * 4;
  float* ad2 = (float*)w;  w += (size_t)N_NODES * 4;
  int* deg   = (int*)w;    w += (size_t)N_NODES * 4;
  int* rowp  = (int*)w;    w += (size_t)50064 * 4;            // N+1, padded
  int* pos   = (int*)w;    w += (size_t)N_NODES * 4;
  int* csr   = (int*)w;    w += (size_t)ET * 4;
  int* bsums = (int*)w;    w += 256;                          // ~113.2 MB total

  float* logits = (float*)d_out;
  float* emb    = (float*)d_out + (size_t)N_NODES * NC;

  hipMemsetAsync(deg, 0, N_NODES * sizeof(int), stream);

  k_gemm1<<<dim3(D1 / TN, (N_NODES + TM - 1) / TM), 256, 0, stream>>>(x, w1, h1, N_NODES);
  k_alphas1<<<(N_NODES * NH + 255) / 256, 256, 0, stream>>>(h1, a_src1, a_dst1, as1, ad1);

  k_degree<<<(ET + 255) / 256, 256, 0, stream>>>(ei, deg);
  k_reduce<<<49, 1024, 0, stream>>>(deg, bsums);
  k_scan_small<<<1, 64, 0, stream>>>(bsums, 49);
  k_scan_final<<<49, 1024, 0, stream>>>(deg, bsums, rowp, pos);
  k_scatter<<<(ET + 255) / 256, 256, 0, stream>>>(ei, pos, csr);

  k_agg1<<<(N_NODES + 3) / 4, 256, 0, stream>>>(h1, as1, ad1, rowp, csr, b1, emb);

  k_gemm2<<<N_NODES, 256, 0, stream>>>(emb, w2, h2);
  k_alphas2<<<(N_NODES + 255) / 256, 256, 0, stream>>>(h2, a_src2, a_dst2, as2, ad2);
  k_agg2<<<(N_NODES + 3) / 4, 256, 0, stream>>>(h2, as2, ad2, rowp, csr, b2, logits);
}

// Round 2
// 687.187 us; speedup vs baseline: 1.5378x; 1.5378x over previous
//
#include <hip/hip_runtime.h>
#include <math.h>

#define N_NODES 50000
#define M_PAD   50048            // 391 * 128
#define N_EDGES 800000
#define ET (N_EDGES + N_NODES)   // 850000 with self loops
#define NF 512
#define HC 64
#define NH 8
#define D1 512                   // NH*HC
#define NC 16
#define NEG_SLOPE 0.2f

typedef __attribute__((ext_vector_type(8))) short bf16x8;
typedef __attribute__((ext_vector_type(4))) float floatx4;

static __device__ __forceinline__ float b2f(unsigned short u) {
  union { unsigned int i; float f; } v; v.i = ((unsigned int)u) << 16; return v.f;
}
static __device__ __forceinline__ unsigned short f2b(float f) {
  union { float f; unsigned int i; } v; v.f = f;
  unsigned int r = v.i + 0x7fffu + ((v.i >> 16) & 1u);
  return (unsigned short)(r >> 16);
}

static __device__ __forceinline__ void async_cp16(const void* g, void* l) {
  __builtin_amdgcn_global_load_lds(
      (const __attribute__((address_space(1))) unsigned int*)g,
      (__attribute__((address_space(3))) unsigned int*)l, 16, 0, 0);
}

// ---------------- cast x (fp32) -> xb (bf16), zero-padded to M_PAD rows ------
__global__ __launch_bounds__(256) void k_cast_x(const float* __restrict__ x,
                                                unsigned short* __restrict__ xb) {
  size_t i = ((size_t)blockIdx.x * 256 + threadIdx.x) * 8;
  if (i >= (size_t)M_PAD * NF) return;
  int row = (int)(i >> 9);
  union { unsigned short s[8]; uint4 v; } u;
  if (row < N_NODES) {
    float4 v0 = *(const float4*)&x[i];
    float4 v1 = *(const float4*)&x[i + 4];
    u.s[0] = f2b(v0.x); u.s[1] = f2b(v0.y); u.s[2] = f2b(v0.z); u.s[3] = f2b(v0.w);
    u.s[4] = f2b(v1.x); u.s[5] = f2b(v1.y); u.s[6] = f2b(v1.z); u.s[7] = f2b(v1.w);
  } else {
    u.v = make_uint4(0, 0, 0, 0);
  }
  *(uint4*)&xb[i] = u.v;
}

// ---------------- transpose + cast w1 -> w1t (bf16, [n][k]) ------------------
__global__ __launch_bounds__(256) void k_w1t(const float* __restrict__ w1,
                                             unsigned short* __restrict__ w1t) {
  __shared__ float t[32][33];
  int tx = threadIdx.x & 31, ty = threadIdx.x >> 5;   // ty 0..7
  int k0 = blockIdx.x * 32, n0 = blockIdx.y * 32;
  for (int r = ty; r < 32; r += 8)
    t[r][tx] = w1[(size_t)(k0 + r) * D1 + n0 + tx];
  __syncthreads();
  for (int r = ty; r < 32; r += 8)
    w1t[(size_t)(n0 + r) * NF + k0 + tx] = f2b(t[tx][r]);
}

// ---------------- GEMM1: h1b = xb @ w1t^T  (bf16 MFMA, 128x128 tile) ---------
__global__ __launch_bounds__(256) void k_gemm1m(const unsigned short* __restrict__ xb,
                                                const unsigned short* __restrict__ w1t,
                                                unsigned short* __restrict__ h1b) {
  __shared__ unsigned short As[128 * 32];   // [m][k], 64 B rows
  __shared__ unsigned short Bs[128 * 32];   // [n][k], 64 B rows
  const int tid  = threadIdx.x;
  const int w    = tid >> 6;
  const int lane = tid & 63;
  const int l16  = lane & 15;
  const int quad = lane >> 4;
  const int bm = blockIdx.y * 128;
  const int bn = blockIdx.x * 128;
  const int wr = (w >> 1) * 64;
  const int wc = (w & 1) * 64;

  floatx4 acc[4][4] = {};

  const int c0 = 2 * w, c1 = 2 * w + 1;
  const unsigned short* ga0 = xb  + (size_t)(bm + c0 * 16 + (lane >> 2)) * NF + (lane & 3) * 8;
  const unsigned short* ga1 = xb  + (size_t)(bm + c1 * 16 + (lane >> 2)) * NF + (lane & 3) * 8;
  const unsigned short* gb0 = w1t + (size_t)(bn + c0 * 16 + (lane >> 2)) * NF + (lane & 3) * 8;
  const unsigned short* gb1 = w1t + (size_t)(bn + c1 * 16 + (lane >> 2)) * NF + (lane & 3) * 8;
  unsigned short* la0 = &As[c0 * 512];
  unsigned short* la1 = &As[c1 * 512];
  unsigned short* lb0 = &Bs[c0 * 512];
  unsigned short* lb1 = &Bs[c1 * 512];

  for (int k0 = 0; k0 < NF; k0 += 32) {
    async_cp16(ga0, la0);
    async_cp16(ga1, la1);
    async_cp16(gb0, lb0);
    async_cp16(gb1, lb1);
    ga0 += 32; ga1 += 32; gb0 += 32; gb1 += 32;
    __syncthreads();
    bf16x8 af[4], bfr[4];
#pragma unroll
    for (int i = 0; i < 4; ++i)
      af[i] = *(const bf16x8*)&As[(wr + i * 16 + l16) * 32 + quad * 8];
#pragma unroll
    for (int j = 0; j < 4; ++j)
      bfr[j] = *(const bf16x8*)&Bs[(wc + j * 16 + l16) * 32 + quad * 8];
#pragma unroll
    for (int i = 0; i < 4; ++i)
#pragma unroll
      for (int j = 0; j < 4; ++j)
        acc[i][j] = __builtin_amdgcn_mfma_f32_16x16x32_bf16(af[i], bfr[j], acc[i][j], 0, 0, 0);
    __syncthreads();
  }

#pragma unroll
  for (int i = 0; i < 4; ++i)
#pragma unroll
    for (int j = 0; j < 4; ++j) {
      int col = bn + wc + j * 16 + l16;
#pragma unroll
      for (int r = 0; r < 4; ++r) {
        int row = bm + wr + i * 16 + quad * 4 + r;
        h1b[(size_t)row * D1 + col] = f2b(acc[i][j][r]);
      }
    }
}

// ---------------- per-node attention logits, layer 1 -------------------------
__global__ void k_alphas1(const unsigned short* __restrict__ h1b,
                          const float* __restrict__ a_src,
                          const float* __restrict__ a_dst,
                          float* __restrict__ as1, float* __restrict__ ad1) {
  int i = blockIdx.x * 256 + threadIdx.x;
  if (i >= N_NODES * NH) return;
  int n = i >> 3, hd = i & 7;
  const unsigned short* hp = h1b + (size_t)n * D1 + hd * HC;
  const float* aw = a_src + hd * HC;
  const float* dw = a_dst + hd * HC;
  float s = 0.f, d = 0.f;
#pragma unroll
  for (int c = 0; c < HC; c += 8) {
    bf16x8 hv = *(const bf16x8*)&hp[c];
#pragma unroll
    for (int j = 0; j < 8; ++j) {
      float v = b2f((unsigned short)hv[j]);
      s += v * aw[c + j];
      d += v * dw[c + j];
    }
  }
  as1[i] = s; ad1[i] = d;
}

// ---------------- CSR construction -------------------------------------------
__global__ void k_degree(const int* __restrict__ ei, int* __restrict__ deg) {
  int i = blockIdx.x * 256 + threadIdx.x;
  if (i >= ET) return;
  int dst = (i < N_EDGES) ? ei[N_EDGES + i] : (i - N_EDGES);
  atomicAdd(&deg[dst], 1);
}

__global__ void k_reduce(const int* __restrict__ deg, int* __restrict__ bsums) {
  __shared__ int s[1024];
  int i = blockIdx.x * 1024 + threadIdx.x;
  s[threadIdx.x] = (i < N_NODES) ? deg[i] : 0;
  __syncthreads();
  for (int off = 512; off > 0; off >>= 1) {
    if (threadIdx.x < off) s[threadIdx.x] += s[threadIdx.x + off];
    __syncthreads();
  }
  if (threadIdx.x == 0) bsums[blockIdx.x] = s[0];
}

__global__ void k_scan_small(int* __restrict__ bsums, int nb) {
  int lane = threadIdx.x;
  int v = (lane < nb) ? bsums[lane] : 0;
  int orig = v;
  for (int off = 1; off < 64; off <<= 1) {
    int u = __shfl_up(v, off);
    if (lane >= off) v += u;
  }
  __syncthreads();
  if (lane < nb) bsums[lane] = v - orig;   // exclusive
}

__global__ void k_scan_final(const int* __restrict__ deg,
                             const int* __restrict__ bsums_ex,
                             int* __restrict__ rowp, int* __restrict__ pos) {
  __shared__ int s[1024];
  int i = blockIdx.x * 1024 + threadIdx.x;
  int v = (i < N_NODES) ? deg[i] : 0;
  s[threadIdx.x] = v;
  __syncthreads();
  for (int off = 1; off < 1024; off <<= 1) {
    int t = (threadIdx.x >= off) ? s[threadIdx.x - off] : 0;
    __syncthreads();
    s[threadIdx.x] += t;
    __syncthreads();
  }
  int inc = s[threadIdx.x];
  int ex  = inc - v + bsums_ex[blockIdx.x];
  if (i < N_NODES) { rowp[i] = ex; pos[i] = ex; }
  if (i == N_NODES - 1) rowp[N_NODES] = ex + v;
}

__global__ void k_scatter(const int* __restrict__ ei, int* __restrict__ pos,
                          int* __restrict__ csr) {
  int i = blockIdx.x * 256 + threadIdx.x;
  if (i >= ET) return;
  int s, d;
  if (i < N_EDGES) { s = ei[i]; d = ei[N_EDGES + i]; }
  else             { s = d = i - N_EDGES; }
  int slot = atomicAdd(&pos[d], 1);
  csr[slot] = s;
}

// ---------------- layer-1 aggregation: one wave per destination node ---------
// lane owns channels lane*8 .. lane*8+7 (all in head lane>>3); one 16B gather/edge
__global__ __launch_bounds__(256) void k_agg1(const unsigned short* __restrict__ h1b,
                                              const float* __restrict__ as1,
                                              const float* __restrict__ ad1,
                                              const int* __restrict__ rowp,
                                              const int* __restrict__ csr,
                                              const float* __restrict__ b1,
                                              float* __restrict__ emb) {
  const int wid  = threadIdx.x >> 6;
  const int lane = threadIdx.x & 63;
  const int node = blockIdx.x * 4 + wid;
  if (node >= N_NODES) return;
  const int start = rowp[node], end = rowp[node + 1];
  const int head = lane >> 3;
  const float adv = ad1[node * NH + head];

  // pass 1: per-head denominator; lanes 8h..8h+7 split edges of head h
  float den = 0.f;
  for (int base = start; base < end; base += 8) {
    int slot = base + (lane & 7);
    if (slot < end) {
      int src = csr[slot];
      float e = as1[src * NH + head] + adv;
      e = (e >= 0.f) ? e : NEG_SLOPE * e;
      den += __expf(e);
    }
  }
  den += __shfl_xor(den, 1);
  den += __shfl_xor(den, 2);
  den += __shfl_xor(den, 4);
  const float rden = 1.f / den;

  // pass 2: weighted gather-sum
  float acc[8] = {};
  for (int j = start; j < end; ++j) {
    int src = csr[j];
    float e = as1[src * NH + head] + adv;
    e = (e >= 0.f) ? e : NEG_SLOPE * e;
    float wgt = __expf(e) * rden;
    bf16x8 hv = *(const bf16x8*)&h1b[(size_t)src * D1 + lane * 8];
#pragma unroll
    for (int jj = 0; jj < 8; ++jj) acc[jj] += wgt * b2f((unsigned short)hv[jj]);
  }
  const float4 bb0 = *(const float4*)&b1[lane * 8];
  const float4 bb1 = *(const float4*)&b1[lane * 8 + 4];
  float4 o0 = make_float4(acc[0] + bb0.x, acc[1] + bb0.y, acc[2] + bb0.z, acc[3] + bb0.w);
  float4 o1 = make_float4(acc[4] + bb1.x, acc[5] + bb1.y, acc[6] + bb1.z, acc[7] + bb1.w);
  *(float4*)&emb[(size_t)node * D1 + lane * 8]     = o0;
  *(float4*)&emb[(size_t)node * D1 + lane * 8 + 4] = o1;
}

// ---------------- layer 2: h2 = elu(emb) @ W2 --------------------------------
__global__ __launch_bounds__(256) void k_gemm2(const float* __restrict__ emb,
                                               const float* __restrict__ W2,
                                               float* __restrict__ h2) {
  __shared__ float sx[D1];
  __shared__ float red[16][17];
  const int node = blockIdx.x;
  const int tid = threadIdx.x;
#pragma unroll
  for (int v = 0; v < 2; ++v) {
    int c = tid + v * 256;
    float x = emb[(size_t)node * D1 + c];
    sx[c] = (x > 0.f) ? x : expm1f(x);
  }
  __syncthreads();
  const int c = tid & 15;   // output channel
  const int g = tid >> 4;   // 0..15 partial group
  float s = 0.f;
  for (int k = g; k < D1; k += 16) s += sx[k] * W2[k * NC + c];
  red[c][g] = s;
  __syncthreads();
  if (tid < 16) {
    float t = 0.f;
#pragma unroll
    for (int g2 = 0; g2 < 16; ++g2) t += red[tid][g2];
    h2[(size_t)node * NC + tid] = t;
  }
}

__global__ void k_alphas2(const float* __restrict__ h2,
                          const float* __restrict__ a_src,
                          const float* __restrict__ a_dst,
                          float* __restrict__ as2, float* __restrict__ ad2) {
  int n = blockIdx.x * 256 + threadIdx.x;
  if (n >= N_NODES) return;
  float s = 0.f, d = 0.f;
#pragma unroll
  for (int c = 0; c < NC; ++c) {
    float v = h2[(size_t)n * NC + c];
    s += v * a_src[c];
    d += v * a_dst[c];
  }
  as2[n] = s; ad2[n] = d;
}

__global__ __launch_bounds__(256) void k_agg2(const float* __restrict__ h2,
                                              const float* __restrict__ as2,
                                              const float* __restrict__ ad2,
                                              const int* __restrict__ rowp,
                                              const int* __restrict__ csr,
                                              const float* __restrict__ b2,
                                              float* __restrict__ logits) {
  const int wid  = threadIdx.x >> 6;
  const int lane = threadIdx.x & 63;
  const int node = blockIdx.x * 4 + wid;
  if (node >= N_NODES) return;
  const int start = rowp[node], end = rowp[node + 1];
  const float adv = ad2[node];

  float den = 0.f;
  for (int j = start + lane; j < end; j += 64) {
    int src = csr[j];
    float e = as2[src] + adv;
    e = (e >= 0.f) ? e : NEG_SLOPE * e;
    den += __expf(e);
  }
  for (int off = 32; off > 0; off >>= 1) den += __shfl_xor(den, off);
  float rd = 1.f / den;

  float acc = 0.f;
  for (int base = start; base < end; base += 4) {
    int j = base + (lane >> 4);
    if (j < end) {
      int src = csr[j];
      float e = as2[src] + adv;
      e = (e >= 0.f) ? e : NEG_SLOPE * e;
      float alpha = __expf(e) * rd;
      acc += alpha * h2[(size_t)src * NC + (lane & 15)];
    }
  }
  acc += __shfl_xor(acc, 16);
  acc += __shfl_xor(acc, 32);
  if (lane < 16) logits[(size_t)node * NC + lane] = acc + b2[lane];
}

// ---------------- launcher ---------------------------------------------------
extern "C" void kernel_launch(void* const* d_in, const int* in_sizes, int n_in,
                              void* d_out, int out_size, void* d_ws, size_t ws_size,
                              hipStream_t stream) {
  const float* x      = (const float*)d_in[0];
  const int*   ei     = (const int*)d_in[1];
  const float* w1     = (const float*)d_in[2];
  const float* a_src1 = (const float*)d_in[3];
  const float* a_dst1 = (const float*)d_in[4];
  const float* b1     = (const float*)d_in[5];
  const float* w2     = (const float*)d_in[6];
  const float* a_src2 = (const float*)d_in[7];
  const float* a_dst2 = (const float*)d_in[8];
  const float* b2     = (const float*)d_in[9];

  char* w = (char*)d_ws;
  char* xb_region = w;
  unsigned short* xb  = (unsigned short*)w; w += (size_t)M_PAD * NF * 2;   // 51.25 MB
  unsigned short* h1b = (unsigned short*)w; w += (size_t)M_PAD * D1 * 2;   // 51.25 MB
  unsigned short* w1t = (unsigned short*)w; w += (size_t)NF * D1 * 2;      // 0.5 MB
  float* as1 = (float*)w;  w += (size_t)N_NODES * NH * 4;
  float* ad1 = (float*)w;  w += (size_t)N_NODES * NH * 4;
  int* deg   = (int*)w;    w += (size_t)N_NODES * 4;
  int* rowp  = (int*)w;    w += (size_t)50064 * 4;
  int* pos   = (int*)w;    w += (size_t)N_NODES * 4;
  int* csr   = (int*)w;    w += (size_t)ET * 4;
  int* bsums = (int*)w;    w += 256;
  // layer-2 temporaries alias the (dead-after-gemm1) xb region
  float* h2  = (float*)xb_region;                                   // 3.2 MB
  float* as2 = (float*)(xb_region + (size_t)N_NODES * NC * 4);
  float* ad2 = (float*)(xb_region + (size_t)N_NODES * NC * 4 + (size_t)N_NODES * 4);

  float* logits = (float*)d_out;
  float* emb    = (float*)d_out + (size_t)N_NODES * NC;

  hipMemsetAsync(deg, 0, N_NODES * sizeof(int), stream);

  k_cast_x<<<(int)(((size_t)M_PAD * NF / 8 + 255) / 256), 256, 0, stream>>>(x, xb);
  k_w1t<<<dim3(16, 16), 256, 0, stream>>>(w1, w1t);
  k_gemm1m<<<dim3(4, M_PAD / 128), 256, 0, stream>>>(xb, w1t, h1b);
  k_alphas1<<<(N_NODES * NH + 255) / 256, 256, 0, stream>>>(h1b, a_src1, a_dst1, as1, ad1);

  k_degree<<<(ET + 255) / 256, 256, 0, stream>>>(ei, deg);
  k_reduce<<<49, 1024, 0, stream>>>(deg, bsums);
  k_scan_small<<<1, 64, 0, stream>>>(bsums, 49);
  k_scan_final<<<49, 1024, 0, stream>>>(deg, bsums, rowp, pos);
  k_scatter<<<(ET + 255) / 256, 256, 0, stream>>>(ei, pos, csr);

  k_agg1<<<(N_NODES + 3) / 4, 256, 0, stream>>>(h1b, as1, ad1, rowp, csr, b1, emb);

  k_gemm2<<<N_NODES, 256, 0, stream>>>(emb, w2, h2);
  k_alphas2<<<(N_NODES + 255) / 256, 256, 0, stream>>>(h2, a_src2, a_dst2, as2, ad2);
  k_agg2<<<(N_NODES + 3) / 4, 256, 0, stream>>>(h2, as2, ad2, rowp, csr, b2, logits);
}

// Round 3
// 662.554 us; speedup vs baseline: 1.5950x; 1.0372x over previous
//
#include <hip/hip_runtime.h>
#include <math.h>

#define N_NODES 50000
#define M_PAD   50048            // 391 * 128
#define N_EDGES 800000
#define ET (N_EDGES + N_NODES)   // 850000 with self loops
#define NF 512
#define HC 64
#define NH 8
#define D1 512                   // NH*HC
#define NC 16
#define NEG_SLOPE 0.2f

typedef __attribute__((ext_vector_type(8))) short bf16x8;
typedef __attribute__((ext_vector_type(4))) float floatx4;

static __device__ __forceinline__ float b2f(unsigned short u) {
  union { unsigned int i; float f; } v; v.i = ((unsigned int)u) << 16; return v.f;
}
static __device__ __forceinline__ unsigned short f2b(float f) {
  union { float f; unsigned int i; } v; v.f = f;
  unsigned int r = v.i + 0x7fffu + ((v.i >> 16) & 1u);
  return (unsigned short)(r >> 16);
}

static __device__ __forceinline__ void async_cp16(const void* g, void* l) {
  __builtin_amdgcn_global_load_lds(
      (const __attribute__((address_space(1))) unsigned int*)g,
      (__attribute__((address_space(3))) unsigned int*)l, 16, 0, 0);
}

// ---------------- cast x (fp32) -> xb (bf16), zero-padded to M_PAD rows ------
__global__ __launch_bounds__(256) void k_cast_x(const float* __restrict__ x,
                                                unsigned short* __restrict__ xb) {
  size_t i = ((size_t)blockIdx.x * 256 + threadIdx.x) * 8;
  if (i >= (size_t)M_PAD * NF) return;
  int row = (int)(i >> 9);
  union { unsigned short s[8]; uint4 v; } u;
  if (row < N_NODES) {
    float4 v0 = *(const float4*)&x[i];
    float4 v1 = *(const float4*)&x[i + 4];
    u.s[0] = f2b(v0.x); u.s[1] = f2b(v0.y); u.s[2] = f2b(v0.z); u.s[3] = f2b(v0.w);
    u.s[4] = f2b(v1.x); u.s[5] = f2b(v1.y); u.s[6] = f2b(v1.z); u.s[7] = f2b(v1.w);
  } else {
    u.v = make_uint4(0, 0, 0, 0);
  }
  *(uint4*)&xb[i] = u.v;
}

// ---------------- transpose + cast w1 -> w1t (bf16, [n][k]) ------------------
__global__ __launch_bounds__(256) void k_w1t(const float* __restrict__ w1,
                                             unsigned short* __restrict__ w1t) {
  __shared__ float t[32][33];
  int tx = threadIdx.x & 31, ty = threadIdx.x >> 5;   // ty 0..7
  int k0 = blockIdx.x * 32, n0 = blockIdx.y * 32;
  for (int r = ty; r < 32; r += 8)
    t[r][tx] = w1[(size_t)(k0 + r) * D1 + n0 + tx];
  __syncthreads();
  for (int r = ty; r < 32; r += 8)
    w1t[(size_t)(n0 + r) * NF + k0 + tx] = f2b(t[tx][r]);
}

// ---------------- GEMM1: h1b = xb @ w1t^T  (bf16 MFMA, 128x128 tile) ---------
__global__ __launch_bounds__(256) void k_gemm1m(const unsigned short* __restrict__ xb,
                                                const unsigned short* __restrict__ w1t,
                                                unsigned short* __restrict__ h1b) {
  __shared__ unsigned short As[128 * 32];   // [m][k], 64 B rows
  __shared__ unsigned short Bs[128 * 32];   // [n][k], 64 B rows
  const int tid  = threadIdx.x;
  const int w    = tid >> 6;
  const int lane = tid & 63;
  const int l16  = lane & 15;
  const int quad = lane >> 4;
  const int bm = blockIdx.y * 128;
  const int bn = blockIdx.x * 128;
  const int wr = (w >> 1) * 64;
  const int wc = (w & 1) * 64;

  floatx4 acc[4][4] = {};

  const int c0 = 2 * w, c1 = 2 * w + 1;
  const unsigned short* ga0 = xb  + (size_t)(bm + c0 * 16 + (lane >> 2)) * NF + (lane & 3) * 8;
  const unsigned short* ga1 = xb  + (size_t)(bm + c1 * 16 + (lane >> 2)) * NF + (lane & 3) * 8;
  const unsigned short* gb0 = w1t + (size_t)(bn + c0 * 16 + (lane >> 2)) * NF + (lane & 3) * 8;
  const unsigned short* gb1 = w1t + (size_t)(bn + c1 * 16 + (lane >> 2)) * NF + (lane & 3) * 8;
  unsigned short* la0 = &As[c0 * 512];
  unsigned short* la1 = &As[c1 * 512];
  unsigned short* lb0 = &Bs[c0 * 512];
  unsigned short* lb1 = &Bs[c1 * 512];

  for (int k0 = 0; k0 < NF; k0 += 32) {
    async_cp16(ga0, la0);
    async_cp16(ga1, la1);
    async_cp16(gb0, lb0);
    async_cp16(gb1, lb1);
    ga0 += 32; ga1 += 32; gb0 += 32; gb1 += 32;
    __syncthreads();
    bf16x8 af[4], bfr[4];
#pragma unroll
    for (int i = 0; i < 4; ++i)
      af[i] = *(const bf16x8*)&As[(wr + i * 16 + l16) * 32 + quad * 8];
#pragma unroll
    for (int j = 0; j < 4; ++j)
      bfr[j] = *(const bf16x8*)&Bs[(wc + j * 16 + l16) * 32 + quad * 8];
#pragma unroll
    for (int i = 0; i < 4; ++i)
#pragma unroll
      for (int j = 0; j < 4; ++j)
        acc[i][j] = __builtin_amdgcn_mfma_f32_16x16x32_bf16(af[i], bfr[j], acc[i][j], 0, 0, 0);
    __syncthreads();
  }

#pragma unroll
  for (int i = 0; i < 4; ++i)
#pragma unroll
    for (int j = 0; j < 4; ++j) {
      int col = bn + wc + j * 16 + l16;
#pragma unroll
      for (int r = 0; r < 4; ++r) {
        int row = bm + wr + i * 16 + quad * 4 + r;
        h1b[(size_t)row * D1 + col] = f2b(acc[i][j][r]);
      }
    }
}

// ---------------- per-node attention logits, layer 1 -------------------------
__global__ void k_alphas1(const unsigned short* __restrict__ h1b,
                          const float* __restrict__ a_src,
                          const float* __restrict__ a_dst,
                          float* __restrict__ as1, float* __restrict__ ad1) {
  int i = blockIdx.x * 256 + threadIdx.x;
  if (i >= N_NODES * NH) return;
  int n = i >> 3, hd = i & 7;
  const unsigned short* hp = h1b + (size_t)n * D1 + hd * HC;
  const float* aw = a_src + hd * HC;
  const float* dw = a_dst + hd * HC;
  float s = 0.f, d = 0.f;
#pragma unroll
  for (int c = 0; c < HC; c += 8) {
    bf16x8 hv = *(const bf16x8*)&hp[c];
#pragma unroll
    for (int j = 0; j < 8; ++j) {
      float v = b2f((unsigned short)hv[j]);
      s += v * aw[c + j];
      d += v * dw[c + j];
    }
  }
  as1[i] = s; ad1[i] = d;
}

// ---------------- CSR construction -------------------------------------------
__global__ void k_degree(const int* __restrict__ ei, int* __restrict__ deg) {
  int i = blockIdx.x * 256 + threadIdx.x;
  if (i >= ET) return;
  int dst = (i < N_EDGES) ? ei[N_EDGES + i] : (i - N_EDGES);
  atomicAdd(&deg[dst], 1);
}

__global__ void k_reduce(const int* __restrict__ deg, int* __restrict__ bsums) {
  __shared__ int s[1024];
  int i = blockIdx.x * 1024 + threadIdx.x;
  s[threadIdx.x] = (i < N_NODES) ? deg[i] : 0;
  __syncthreads();
  for (int off = 512; off > 0; off >>= 1) {
    if (threadIdx.x < off) s[threadIdx.x] += s[threadIdx.x + off];
    __syncthreads();
  }
  if (threadIdx.x == 0) bsums[blockIdx.x] = s[0];
}

__global__ void k_scan_small(int* __restrict__ bsums, int nb) {
  int lane = threadIdx.x;
  int v = (lane < nb) ? bsums[lane] : 0;
  int orig = v;
  for (int off = 1; off < 64; off <<= 1) {
    int u = __shfl_up(v, off);
    if (lane >= off) v += u;
  }
  __syncthreads();
  if (lane < nb) bsums[lane] = v - orig;   // exclusive
}

__global__ void k_scan_final(const int* __restrict__ deg,
                             const int* __restrict__ bsums_ex,
                             int* __restrict__ rowp, int* __restrict__ pos) {
  __shared__ int s[1024];
  int i = blockIdx.x * 1024 + threadIdx.x;
  int v = (i < N_NODES) ? deg[i] : 0;
  s[threadIdx.x] = v;
  __syncthreads();
  for (int off = 1; off < 1024; off <<= 1) {
    int t = (threadIdx.x >= off) ? s[threadIdx.x - off] : 0;
    __syncthreads();
    s[threadIdx.x] += t;
    __syncthreads();
  }
  int inc = s[threadIdx.x];
  int ex  = inc - v + bsums_ex[blockIdx.x];
  if (i < N_NODES) { rowp[i] = ex; pos[i] = ex; }
  if (i == N_NODES - 1) rowp[N_NODES] = ex + v;
}

__global__ void k_scatter(const int* __restrict__ ei, int* __restrict__ pos,
                          int* __restrict__ csr) {
  int i = blockIdx.x * 256 + threadIdx.x;
  if (i >= ET) return;
  int s, d;
  if (i < N_EDGES) { s = ei[i]; d = ei[N_EDGES + i]; }
  else             { s = d = i - N_EDGES; }
  int slot = atomicAdd(&pos[d], 1);
  csr[slot] = s;
}

// ---------------- layer-1 aggregation: one wave per destination node ---------
// SINGLE pass: acc = sum exp(e)*h, den = sum exp(e) (every lane sums all
// edges -> den needs no cross-lane reduce); out = acc/den. 1-edge prefetch.
__global__ __launch_bounds__(256) void k_agg1(const unsigned short* __restrict__ h1b,
                                              const float* __restrict__ as1,
                                              const float* __restrict__ ad1,
                                              const int* __restrict__ rowp,
                                              const int* __restrict__ csr,
                                              const float* __restrict__ b1,
                                              float* __restrict__ emb) {
  const int wid  = threadIdx.x >> 6;
  const int lane = threadIdx.x & 63;
  const int node = blockIdx.x * 4 + wid;
  if (node >= N_NODES) return;
  const int start = rowp[node], end = rowp[node + 1];
  const int head = lane >> 3;
  const float adv = ad1[node * NH + head];

  // prologue prefetch (>=1 edge always: self loop)
  int src0 = csr[start];
  float al = as1[src0 * NH + head];
  bf16x8 hv = *(const bf16x8*)&h1b[(size_t)src0 * D1 + lane * 8];

  float den = 0.f;
  float acc[8] = {};
  for (int j = start; j < end; ++j) {
    bf16x8 hc = hv;
    float alc = al;
    if (j + 1 < end) {
      int sn = csr[j + 1];
      al = as1[sn * NH + head];
      hv = *(const bf16x8*)&h1b[(size_t)sn * D1 + lane * 8];
    }
    float e = alc + adv;
    e = (e >= 0.f) ? e : NEG_SLOPE * e;
    float wgt = __expf(e);
    den += wgt;
#pragma unroll
    for (int jj = 0; jj < 8; ++jj) acc[jj] += wgt * b2f((unsigned short)hc[jj]);
  }
  const float rden = 1.f / den;

  const float4 bb0 = *(const float4*)&b1[lane * 8];
  const float4 bb1 = *(const float4*)&b1[lane * 8 + 4];
  float4 o0 = make_float4(acc[0] * rden + bb0.x, acc[1] * rden + bb0.y,
                          acc[2] * rden + bb0.z, acc[3] * rden + bb0.w);
  float4 o1 = make_float4(acc[4] * rden + bb1.x, acc[5] * rden + bb1.y,
                          acc[6] * rden + bb1.z, acc[7] * rden + bb1.w);
  *(float4*)&emb[(size_t)node * D1 + lane * 8]     = o0;
  *(float4*)&emb[(size_t)node * D1 + lane * 8 + 4] = o1;
}

// ---------------- layer 2: h2 = elu(emb) @ W2, fused as2/ad2 -----------------
__global__ __launch_bounds__(256) void k_gemm2(const float* __restrict__ emb,
                                               const float* __restrict__ W2,
                                               const float* __restrict__ a_src2,
                                               const float* __restrict__ a_dst2,
                                               float* __restrict__ h2,
                                               float* __restrict__ as2,
                                               float* __restrict__ ad2) {
  __shared__ float sx[D1];
  __shared__ float red[16][17];
  const int node = blockIdx.x;
  const int tid = threadIdx.x;
#pragma unroll
  for (int v = 0; v < 2; ++v) {
    int c = tid + v * 256;
    float x = emb[(size_t)node * D1 + c];
    sx[c] = (x > 0.f) ? x : (__expf(x) - 1.f);
  }
  __syncthreads();
  const int c = tid & 15;   // output channel
  const int g = tid >> 4;   // 0..15 partial group
  float s = 0.f;
  for (int k = g; k < D1; k += 16) s += sx[k] * W2[k * NC + c];
  red[c][g] = s;
  __syncthreads();
  if (tid < 16) {
    float t = 0.f;
#pragma unroll
    for (int g2 = 0; g2 < 16; ++g2) t += red[tid][g2];
    h2[(size_t)node * NC + tid] = t;
    float sa = t * a_src2[tid];
    float da = t * a_dst2[tid];
#pragma unroll
    for (int off = 8; off > 0; off >>= 1) {
      sa += __shfl_xor(sa, off);
      da += __shfl_xor(da, off);
    }
    if (tid == 0) { as2[node] = sa; ad2[node] = da; }
  }
}

// ---------------- layer-2 aggregation: single pass ---------------------------
__global__ __launch_bounds__(256) void k_agg2(const float* __restrict__ h2,
                                              const float* __restrict__ as2,
                                              const float* __restrict__ ad2,
                                              const int* __restrict__ rowp,
                                              const int* __restrict__ csr,
                                              const float* __restrict__ b2,
                                              float* __restrict__ logits) {
  const int wid  = threadIdx.x >> 6;
  const int lane = threadIdx.x & 63;
  const int node = blockIdx.x * 4 + wid;
  if (node >= N_NODES) return;
  const int start = rowp[node], end = rowp[node + 1];
  const float adv = ad2[node];

  float den = 0.f, acc = 0.f;
  for (int base = start; base < end; base += 4) {
    int j = base + (lane >> 4);
    if (j < end) {
      int src = csr[j];
      float e = as2[src] + adv;
      e = (e >= 0.f) ? e : NEG_SLOPE * e;
      float wgt = __expf(e);
      den += wgt;
      acc += wgt * h2[(size_t)src * NC + (lane & 15)];
    }
  }
  acc += __shfl_xor(acc, 16); acc += __shfl_xor(acc, 32);
  den += __shfl_xor(den, 16); den += __shfl_xor(den, 32);
  if (lane < 16) logits[(size_t)node * NC + lane] = acc / den + b2[lane];
}

// ---------------- launcher ---------------------------------------------------
extern "C" void kernel_launch(void* const* d_in, const int* in_sizes, int n_in,
                              void* d_out, int out_size, void* d_ws, size_t ws_size,
                              hipStream_t stream) {
  const float* x      = (const float*)d_in[0];
  const int*   ei     = (const int*)d_in[1];
  const float* w1     = (const float*)d_in[2];
  const float* a_src1 = (const float*)d_in[3];
  const float* a_dst1 = (const float*)d_in[4];
  const float* b1     = (const float*)d_in[5];
  const float* w2     = (const float*)d_in[6];
  const float* a_src2 = (const float*)d_in[7];
  const float* a_dst2 = (const float*)d_in[8];
  const float* b2     = (const float*)d_in[9];

  char* w = (char*)d_ws;
  char* xb_region = w;
  unsigned short* xb  = (unsigned short*)w; w += (size_t)M_PAD * NF * 2;   // 51.25 MB
  unsigned short* h1b = (unsigned short*)w; w += (size_t)M_PAD * D1 * 2;   // 51.25 MB
  unsigned short* w1t = (unsigned short*)w; w += (size_t)NF * D1 * 2;      // 0.5 MB
  float* as1 = (float*)w;  w += (size_t)N_NODES * NH * 4;
  float* ad1 = (float*)w;  w += (size_t)N_NODES * NH * 4;
  int* deg   = (int*)w;    w += (size_t)N_NODES * 4;
  int* rowp  = (int*)w;    w += (size_t)50064 * 4;
  int* pos   = (int*)w;    w += (size_t)N_NODES * 4;
  int* csr   = (int*)w;    w += (size_t)ET * 4;
  int* bsums = (int*)w;    w += 256;
  // layer-2 temporaries alias the (dead-after-gemm1) xb region
  float* h2  = (float*)xb_region;                                   // 3.2 MB
  float* as2 = (float*)(xb_region + (size_t)N_NODES * NC * 4);
  float* ad2 = (float*)(xb_region + (size_t)N_NODES * NC * 4 + (size_t)N_NODES * 4);

  float* logits = (float*)d_out;
  float* emb    = (float*)d_out + (size_t)N_NODES * NC;

  hipMemsetAsync(deg, 0, N_NODES * sizeof(int), stream);

  k_cast_x<<<(int)(((size_t)M_PAD * NF / 8 + 255) / 256), 256, 0, stream>>>(x, xb);
  k_w1t<<<dim3(16, 16), 256, 0, stream>>>(w1, w1t);
  k_gemm1m<<<dim3(4, M_PAD / 128), 256, 0, stream>>>(xb, w1t, h1b);
  k_alphas1<<<(N_NODES * NH + 255) / 256, 256, 0, stream>>>(h1b, a_src1, a_dst1, as1, ad1);

  k_degree<<<(ET + 255) / 256, 256, 0, stream>>>(ei, deg);
  k_reduce<<<49, 1024, 0, stream>>>(deg, bsums);
  k_scan_small<<<1, 64, 0, stream>>>(bsums, 49);
  k_scan_final<<<49, 1024, 0, stream>>>(deg, bsums, rowp, pos);
  k_scatter<<<(ET + 255) / 256, 256, 0, stream>>>(ei, pos, csr);

  k_agg1<<<(N_NODES + 3) / 4, 256, 0, stream>>>(h1b, as1, ad1, rowp, csr, b1, emb);

  k_gemm2<<<N_NODES, 256, 0, stream>>>(emb, w2, a_src2, a_dst2, h2, as2, ad2);
  k_agg2<<<(N_NODES + 3) / 4, 256, 0, stream>>>(h2, as2, ad2, rowp, csr, b2, logits);
}